// Round 10
// baseline (119.454 us; speedup 1.0000x reference)
//
#include <hip/hip_runtime.h>
#include <hip/hip_bf16.h>

// out[b,i,j] = sum_h a[h] * tanh(ca[b,i,h] + da[b,j,h] + bias[h])
//   tanh(x) = 1 - 2/(e^{2x}+1);  e^{2x} = (pu*2^16)*pv, pu scaled 2^-16 in prepass.
// Quad common denominator: 14 VALU + 1 v_rcp per 4 h; out = A - 2^-15 * sum(Q).
// coattn v5b: 4 consecutive j per thread. Round-9 bug: (&float4.x)[s] member-
// offset indexing is UB on HIP_vector_type and clang dropped the s>=1 chains
// (output = const A on 3/4 lanes -> absmax 7.20 = max|ref-A|). Fixed with
// plain float arrays + compile-time indices (registers, no scratch).
// Output FLOAT32 (reference dtype).

#define BB    8
#define NC    1024
#define ND    1024
#define DD    64
#define HH    32
#define CHUNK 8
#define C2    2.885390081777927f        // 2*log2(e)
#define EPS16 1.52587890625e-05f        // 2^-16 (exact)
#define SCALE (-3.0517578125e-05f)      // -2^-15 (exact)

__global__ __launch_bounds__(256) void proj_cell_kernel(
    const float* __restrict__ cell, const float* __restrict__ w_k,
    const float* __restrict__ bias, float* __restrict__ pu)
{
    int tid = threadIdx.x;
    int h = tid & 31;
    int i = blockIdx.x * 8 + (tid >> 5);
    int b = blockIdx.y;
    const float* crow = cell + ((size_t)(b * NC + i)) * DD;
    float s = bias[h];
    #pragma unroll
    for (int d = 0; d < DD; ++d)
        s = fmaf(crow[d], w_k[d * HH + h], s);
    // pu' = 2^-16 * e^{2*(ca+bias)}  (scale folded into the exponent, exact)
    pu[((size_t)(b * NC + i)) * HH + h] = exp2f(fmaf(C2, s, -16.0f));
}

// pv layout: [B][H][ND] so the main kernel's pv loads are j-coalesced.
__global__ __launch_bounds__(256) void proj_drug_kernel(
    const float* __restrict__ drug, const float* __restrict__ w_q,
    float* __restrict__ pv)
{
    __shared__ float sd[64][65];   // +1 pad breaks the 32-bank alias
    int tid = threadIdx.x;
    int b = blockIdx.y;
    int j0 = blockIdx.x * 64;
    const float* dbase = drug + ((size_t)(b * ND + j0)) * DD;
    #pragma unroll
    for (int k = 0; k < 16; ++k) {
        int idx = k * 256 + tid;           // coalesced global read
        sd[idx >> 6][idx & 63] = dbase[idx];
    }
    __syncthreads();
    int jl = tid & 63;       // lane = j  -> coalesced pv writes
    int hg = tid >> 6;       // 0..3, wave-uniform h
    #pragma unroll
    for (int hh = 0; hh < 8; ++hh) {
        int h = hg * 8 + hh;
        float s = 0.f;
        #pragma unroll
        for (int d = 0; d < DD; ++d)
            s = fmaf(sd[jl][d], w_q[d * HH + h], s);
        pv[((size_t)(b * HH + h)) * ND + j0 + jl] = exp2f(C2 * s);
    }
}

__global__ __launch_bounds__(256) void coattn_kernel(
    const float* __restrict__ pu, const float* __restrict__ pv,
    const float* __restrict__ a, float* __restrict__ out)
{
    __shared__ float spu[CHUNK * HH];   // 8 rows x 32 h = 1 KB
    int tid = threadIdx.x;
    int j4  = blockIdx.x * 1024 + tid * 4;   // four consecutive j per thread
    int b   = blockIdx.z;
    int i0  = blockIdx.y * CHUNK;

    // Cooperative pu-tile stage: 256 floats = one per thread, coalesced.
    spu[tid] = pu[((size_t)(b * NC + i0)) * HH + tid];

    // Per-thread pv columns: float4 load per h, then well-defined local array.
    // All indices are compile-time constants after unroll -> pure registers.
    float pvr[HH][4];
    #pragma unroll
    for (int h = 0; h < HH; ++h) {
        float4 t = *reinterpret_cast<const float4*>(&pv[((size_t)(b * HH + h)) * ND + j4]);
        pvr[h][0] = t.x; pvr[h][1] = t.y; pvr[h][2] = t.z; pvr[h][3] = t.w;
    }

    // a[] loads are wave-uniform -> scalar path.
    float av[HH];
    #pragma unroll
    for (int h = 0; h < HH; ++h)
        av[h] = a[h];
    float A = 0.f;
    #pragma unroll
    for (int h = 0; h < HH; ++h)
        A += av[h];

    __syncthreads();

    float* orow = out + ((size_t)(b * NC + i0)) * ND + j4;

    #pragma unroll
    for (int ii = 0; ii < CHUNK; ++ii) {
        float acc0[4] = {0.f, 0.f, 0.f, 0.f};
        float acc1[4] = {0.f, 0.f, 0.f, 0.f};
        #pragma unroll
        for (int q = 0; q < HH / 4; ++q) {
            // wave-uniform LDS broadcast: one ds_read_b128 per quad
            float4 pqv = reinterpret_cast<const float4*>(spu + ii * HH)[q];
            float pq[4];
            pq[0] = pqv.x; pq[1] = pqv.y; pq[2] = pqv.z; pq[3] = pqv.w;
            float s0 = av[4 * q + 0], s1 = av[4 * q + 1];
            float s2 = av[4 * q + 2], s3 = av[4 * q + 3];

            #pragma unroll
            for (int s = 0; s < 4; ++s) {   // 4 independent j-chains
                float u = fmaf(pq[0], pvr[4 * q + 0][s], EPS16);
                float v = fmaf(pq[1], pvr[4 * q + 1][s], EPS16);
                float w = fmaf(pq[2], pvr[4 * q + 2][s], EPS16);
                float z = fmaf(pq[3], pvr[4 * q + 3][s], EPS16);
                float n01 = fmaf(s1, u, s0 * v);
                float d01 = u * v;
                float n23 = fmaf(s3, w, s2 * z);
                float d23 = w * z;
                float den = d01 * d23;                  // [2^-64, ~3e8]: fp32-safe
                float num = fmaf(n23, d01, n01 * d23);  // <= ~3e6: fp32-safe
                float r   = __builtin_amdgcn_rcpf(den);
                if (q & 1) acc1[s] = fmaf(num, r, acc1[s]);
                else       acc0[s] = fmaf(num, r, acc0[s]);
            }
        }
        float4 res;
        res.x = fmaf(acc0[0] + acc1[0], SCALE, A);   // A - 2^-15 * sum
        res.y = fmaf(acc0[1] + acc1[1], SCALE, A);
        res.z = fmaf(acc0[2] + acc1[2], SCALE, A);
        res.w = fmaf(acc0[3] + acc1[3], SCALE, A);
        *reinterpret_cast<float4*>(&orow[(size_t)ii * ND]) = res;
    }
}

extern "C" void kernel_launch(void* const* d_in, const int* in_sizes, int n_in,
                              void* d_out, int out_size, void* d_ws, size_t ws_size,
                              hipStream_t stream) {
    const float* cell = (const float*)d_in[0];
    const float* drug = (const float*)d_in[1];
    const float* w_q  = (const float*)d_in[2];
    const float* w_k  = (const float*)d_in[3];
    const float* bias = (const float*)d_in[4];
    const float* a    = (const float*)d_in[5];
    float* out = (float*)d_out;

    float* pu = (float*)d_ws;                      // [B][NC][H]  = 1 MB  (scaled 2^-16)
    float* pv = pu + (size_t)BB * NC * HH;         // [B][H][ND]  = 1 MB

    proj_cell_kernel<<<dim3(NC / 8, BB), 256, 0, stream>>>(cell, w_k, bias, pu);
    proj_drug_kernel<<<dim3(ND / 64, BB), 256, 0, stream>>>(drug, w_q, pv);
    coattn_kernel<<<dim3(ND / 1024, NC / CHUNK, BB), 256, 0, stream>>>(pu, pv, a, out);
}

// Round 11
// 117.685 us; speedup vs baseline: 1.0150x; 1.0150x over previous
//
#include <hip/hip_runtime.h>
#include <hip/hip_bf16.h>

// out[b,i,j] = sum_h a[h] * tanh(ca[b,i,h] + da[b,j,h] + bias[h])
//   tanh(x) = 1 - 2/(e^{2x}+1);  e^{2x} = (pu*2^16)*pv, pu scaled 2^-16 in prepass.
// Quad common denominator: 14 VALU + 1 v_rcp per 4 h; out = A - 2^-15 * sum(Q).
// coattn v6: round-8 structure (2 j/thread = best: 119.0) + CHUNK=16 so the
// per-block pv-load startup latency (32 vector loads, ~600-900cy) amortizes
// over 2x the compute. pu tile 16x32 = 2 KB LDS, rows read as uniform b128.
// Output FLOAT32 (reference dtype).

#define BB    8
#define NC    1024
#define ND    1024
#define DD    64
#define HH    32
#define CHUNK 16
#define C2    2.885390081777927f        // 2*log2(e)
#define EPS16 1.52587890625e-05f        // 2^-16 (exact)
#define SCALE (-3.0517578125e-05f)      // -2^-15 (exact)

__global__ __launch_bounds__(256) void proj_cell_kernel(
    const float* __restrict__ cell, const float* __restrict__ w_k,
    const float* __restrict__ bias, float* __restrict__ pu)
{
    int tid = threadIdx.x;
    int h = tid & 31;
    int i = blockIdx.x * 8 + (tid >> 5);
    int b = blockIdx.y;
    const float* crow = cell + ((size_t)(b * NC + i)) * DD;
    float s = bias[h];
    #pragma unroll
    for (int d = 0; d < DD; ++d)
        s = fmaf(crow[d], w_k[d * HH + h], s);
    // pu' = 2^-16 * e^{2*(ca+bias)}  (scale folded into the exponent, exact)
    pu[((size_t)(b * NC + i)) * HH + h] = exp2f(fmaf(C2, s, -16.0f));
}

// pv layout: [B][H][ND] so the main kernel's pv loads are j-coalesced.
__global__ __launch_bounds__(256) void proj_drug_kernel(
    const float* __restrict__ drug, const float* __restrict__ w_q,
    float* __restrict__ pv)
{
    __shared__ float sd[64][65];   // +1 pad breaks the 32-bank alias
    int tid = threadIdx.x;
    int b = blockIdx.y;
    int j0 = blockIdx.x * 64;
    const float* dbase = drug + ((size_t)(b * ND + j0)) * DD;
    #pragma unroll
    for (int k = 0; k < 16; ++k) {
        int idx = k * 256 + tid;           // coalesced global read
        sd[idx >> 6][idx & 63] = dbase[idx];
    }
    __syncthreads();
    int jl = tid & 63;       // lane = j  -> coalesced pv writes
    int hg = tid >> 6;       // 0..3, wave-uniform h
    #pragma unroll
    for (int hh = 0; hh < 8; ++hh) {
        int h = hg * 8 + hh;
        float s = 0.f;
        #pragma unroll
        for (int d = 0; d < DD; ++d)
            s = fmaf(sd[jl][d], w_q[d * HH + h], s);
        pv[((size_t)(b * HH + h)) * ND + j0 + jl] = exp2f(C2 * s);
    }
}

__global__ __launch_bounds__(256) void coattn_kernel(
    const float* __restrict__ pu, const float* __restrict__ pv,
    const float* __restrict__ a, float* __restrict__ out)
{
    __shared__ float spu[CHUNK * HH];   // 16 rows x 32 h = 2 KB
    int tid = threadIdx.x;
    int j2  = blockIdx.x * 512 + tid * 2;   // two consecutive j per thread
    int b   = blockIdx.z;
    int i0  = blockIdx.y * CHUNK;

    // Cooperative pu-tile stage: 512 floats = one float2 per thread, coalesced.
    {
        const float* src = pu + ((size_t)(b * NC + i0)) * HH;
        reinterpret_cast<float2*>(spu)[tid] =
            reinterpret_cast<const float2*>(src)[tid];
    }

    // Per-thread pv columns: float2 per h, coalesced dwordx2 across the wave.
    float pvr[HH][2];
    #pragma unroll
    for (int h = 0; h < HH; ++h) {
        float2 t = *reinterpret_cast<const float2*>(&pv[((size_t)(b * HH + h)) * ND + j2]);
        pvr[h][0] = t.x; pvr[h][1] = t.y;
    }

    // a[] loads are wave-uniform -> scalar path.
    float av[HH];
    #pragma unroll
    for (int h = 0; h < HH; ++h)
        av[h] = a[h];
    float A = 0.f;
    #pragma unroll
    for (int h = 0; h < HH; ++h)
        A += av[h];

    __syncthreads();

    float* orow = out + ((size_t)(b * NC + i0)) * ND + j2;

    #pragma unroll
    for (int ii = 0; ii < CHUNK; ++ii) {
        float acc0[2] = {0.f, 0.f};
        float acc1[2] = {0.f, 0.f};
        #pragma unroll
        for (int q = 0; q < HH / 4; ++q) {
            // wave-uniform LDS broadcast: one ds_read_b128 per quad
            float4 pqv = reinterpret_cast<const float4*>(spu + ii * HH)[q];
            float pq[4];
            pq[0] = pqv.x; pq[1] = pqv.y; pq[2] = pqv.z; pq[3] = pqv.w;
            float s0 = av[4 * q + 0], s1 = av[4 * q + 1];
            float s2 = av[4 * q + 2], s3 = av[4 * q + 3];

            #pragma unroll
            for (int s = 0; s < 2; ++s) {   // 2 independent j-chains
                float u = fmaf(pq[0], pvr[4 * q + 0][s], EPS16);
                float v = fmaf(pq[1], pvr[4 * q + 1][s], EPS16);
                float w = fmaf(pq[2], pvr[4 * q + 2][s], EPS16);
                float z = fmaf(pq[3], pvr[4 * q + 3][s], EPS16);
                float n01 = fmaf(s1, u, s0 * v);
                float d01 = u * v;
                float n23 = fmaf(s3, w, s2 * z);
                float d23 = w * z;
                float den = d01 * d23;                  // [2^-64, ~3e8]: fp32-safe
                float num = fmaf(n23, d01, n01 * d23);  // <= ~3e6: fp32-safe
                float r   = __builtin_amdgcn_rcpf(den);
                if (q & 1) acc1[s] = fmaf(num, r, acc1[s]);
                else       acc0[s] = fmaf(num, r, acc0[s]);
            }
        }
        float2 res;
        res.x = fmaf(acc0[0] + acc1[0], SCALE, A);   // A - 2^-15 * sum
        res.y = fmaf(acc0[1] + acc1[1], SCALE, A);
        *reinterpret_cast<float2*>(&orow[(size_t)ii * ND]) = res;
    }
}

extern "C" void kernel_launch(void* const* d_in, const int* in_sizes, int n_in,
                              void* d_out, int out_size, void* d_ws, size_t ws_size,
                              hipStream_t stream) {
    const float* cell = (const float*)d_in[0];
    const float* drug = (const float*)d_in[1];
    const float* w_q  = (const float*)d_in[2];
    const float* w_k  = (const float*)d_in[3];
    const float* bias = (const float*)d_in[4];
    const float* a    = (const float*)d_in[5];
    float* out = (float*)d_out;

    float* pu = (float*)d_ws;                      // [B][NC][H]  = 1 MB  (scaled 2^-16)
    float* pv = pu + (size_t)BB * NC * HH;         // [B][H][ND]  = 1 MB

    proj_cell_kernel<<<dim3(NC / 8, BB), 256, 0, stream>>>(cell, w_k, bias, pu);
    proj_drug_kernel<<<dim3(ND / 64, BB), 256, 0, stream>>>(drug, w_q, pv);
    coattn_kernel<<<dim3(ND / 512, NC / CHUNK, BB), 256, 0, stream>>>(pu, pv, a, out);
}

// Round 14
// 117.406 us; speedup vs baseline: 1.0174x; 1.0024x over previous
//
#include <hip/hip_runtime.h>
#include <hip/hip_bf16.h>

// out[b,i,j] = sum_h a[h] * tanh(ca[b,i,h] + da[b,j,h] + bias[h])
//   tanh(x) = 1 - 2/(e^{2x}+1);  e^{2x} = (pu*2^16)*pv, pu scaled 2^-16 in prepass.
// Quad common denominator: 14 VALU + 1 v_rcp per 4 h; out = A - 2^-15 * sum(Q).
// coattn v7: CHUNK=32 rows/block (amortization trend R7->R8->R11 wins over
// occupancy), 2 j/thread, grid (2,32,8)=512 blocks = exactly 2/CU.
// Row loop unroll 2 (I-cache); quad loop fully unrolled, static indices.
// Prepasses fused into ONE dispatch (block-ranges: drug then cell).
// Output FLOAT32 (reference dtype).
// (Rounds 12 & 13: broker GPUAcquisitionTimeout; identical resubmission.)

#define BB    8
#define NC    1024
#define ND    1024
#define DD    64
#define HH    32
#define CHUNK 32
#define C2    2.885390081777927f        // 2*log2(e)
#define EPS16 1.52587890625e-05f        // 2^-16 (exact)
#define SCALE (-3.0517578125e-05f)      // -2^-15 (exact)

#define DRUG_BLKS (ND / 64)             // 16
#define CELL_BLKS (NC / 8)              // 128

// One dispatch: blocks [0,16) do the drug->pv projection (uses LDS),
// blocks [16,144) do the cell->pu projection. Branch is block-uniform.
__global__ __launch_bounds__(256) void proj_fused_kernel(
    const float* __restrict__ cell, const float* __restrict__ drug,
    const float* __restrict__ w_q,  const float* __restrict__ w_k,
    const float* __restrict__ bias, float* __restrict__ pu,
    float* __restrict__ pv)
{
    __shared__ float sd[64][65];   // +1 pad breaks the 32-bank alias (drug part)
    int tid = threadIdx.x;
    int b   = blockIdx.y;

    if (blockIdx.x < DRUG_BLKS) {
        // ---- pv[b][h][j] = exp2(C2 * (drug@w_q)) ----
        int j0 = blockIdx.x * 64;
        const float* dbase = drug + ((size_t)(b * ND + j0)) * DD;
        #pragma unroll
        for (int k = 0; k < 16; ++k) {
            int idx = k * 256 + tid;           // coalesced global read
            sd[idx >> 6][idx & 63] = dbase[idx];
        }
        __syncthreads();
        int jl = tid & 63;       // lane = j  -> coalesced pv writes
        int hg = tid >> 6;       // 0..3, wave-uniform h
        #pragma unroll
        for (int hh = 0; hh < 8; ++hh) {
            int h = hg * 8 + hh;
            float s = 0.f;
            #pragma unroll
            for (int d = 0; d < DD; ++d)
                s = fmaf(sd[jl][d], w_q[d * HH + h], s);
            pv[((size_t)(b * HH + h)) * ND + j0 + jl] = exp2f(C2 * s);
        }
    } else {
        // ---- pu[b][i][h] = 2^-16 * exp2(C2*(cell@w_k + bias)) ----
        int h = tid & 31;
        int i = (blockIdx.x - DRUG_BLKS) * 8 + (tid >> 5);
        const float* crow = cell + ((size_t)(b * NC + i)) * DD;
        float s = bias[h];
        #pragma unroll
        for (int d = 0; d < DD; ++d)
            s = fmaf(crow[d], w_k[d * HH + h], s);
        pu[((size_t)(b * NC + i)) * HH + h] = exp2f(fmaf(C2, s, -16.0f));
    }
}

__global__ __launch_bounds__(256) void coattn_kernel(
    const float* __restrict__ pu, const float* __restrict__ pv,
    const float* __restrict__ a, float* __restrict__ out)
{
    __shared__ float spu[CHUNK * HH];   // 32 rows x 32 h = 4 KB
    int tid = threadIdx.x;
    int j2  = blockIdx.x * 512 + tid * 2;   // two consecutive j per thread
    int b   = blockIdx.z;
    int i0  = blockIdx.y * CHUNK;

    // Cooperative pu-tile stage: 1024 floats = one float4 per thread, coalesced.
    {
        const float* src = pu + ((size_t)(b * NC + i0)) * HH;
        reinterpret_cast<float4*>(spu)[tid] =
            reinterpret_cast<const float4*>(src)[tid];
    }

    // Per-thread pv columns: float2 per h, coalesced dwordx2 across the wave.
    float pvr[HH][2];
    #pragma unroll
    for (int h = 0; h < HH; ++h) {
        float2 t = *reinterpret_cast<const float2*>(&pv[((size_t)(b * HH + h)) * ND + j2]);
        pvr[h][0] = t.x; pvr[h][1] = t.y;
    }

    // a[] loads are wave-uniform -> scalar path.
    float av[HH];
    #pragma unroll
    for (int h = 0; h < HH; ++h)
        av[h] = a[h];
    float A = 0.f;
    #pragma unroll
    for (int h = 0; h < HH; ++h)
        A += av[h];

    __syncthreads();

    float* orow = out + ((size_t)(b * NC + i0)) * ND + j2;

    #pragma unroll 2
    for (int ii = 0; ii < CHUNK; ++ii) {
        float acc0[2] = {0.f, 0.f};
        float acc1[2] = {0.f, 0.f};
        #pragma unroll
        for (int q = 0; q < HH / 4; ++q) {
            // wave-uniform LDS broadcast: one ds_read_b128 per quad
            float4 pqv = reinterpret_cast<const float4*>(spu + ii * HH)[q];
            float pq[4];
            pq[0] = pqv.x; pq[1] = pqv.y; pq[2] = pqv.z; pq[3] = pqv.w;
            float s0 = av[4 * q + 0], s1 = av[4 * q + 1];
            float s2 = av[4 * q + 2], s3 = av[4 * q + 3];

            #pragma unroll
            for (int s = 0; s < 2; ++s) {   // 2 independent j-chains
                float u = fmaf(pq[0], pvr[4 * q + 0][s], EPS16);
                float v = fmaf(pq[1], pvr[4 * q + 1][s], EPS16);
                float w = fmaf(pq[2], pvr[4 * q + 2][s], EPS16);
                float z = fmaf(pq[3], pvr[4 * q + 3][s], EPS16);
                float n01 = fmaf(s1, u, s0 * v);
                float d01 = u * v;
                float n23 = fmaf(s3, w, s2 * z);
                float d23 = w * z;
                float den = d01 * d23;                  // [2^-64, ~3e8]: fp32-safe
                float num = fmaf(n23, d01, n01 * d23);  // <= ~3e6: fp32-safe
                float r   = __builtin_amdgcn_rcpf(den);
                if (q & 1) acc1[s] = fmaf(num, r, acc1[s]);
                else       acc0[s] = fmaf(num, r, acc0[s]);
            }
        }
        float2 res;
        res.x = fmaf(acc0[0] + acc1[0], SCALE, A);   // A - 2^-15 * sum
        res.y = fmaf(acc0[1] + acc1[1], SCALE, A);
        *reinterpret_cast<float2*>(&orow[(size_t)ii * ND]) = res;
    }
}

extern "C" void kernel_launch(void* const* d_in, const int* in_sizes, int n_in,
                              void* d_out, int out_size, void* d_ws, size_t ws_size,
                              hipStream_t stream) {
    const float* cell = (const float*)d_in[0];
    const float* drug = (const float*)d_in[1];
    const float* w_q  = (const float*)d_in[2];
    const float* w_k  = (const float*)d_in[3];
    const float* bias = (const float*)d_in[4];
    const float* a    = (const float*)d_in[5];
    float* out = (float*)d_out;

    float* pu = (float*)d_ws;                      // [B][NC][H]  = 1 MB  (scaled 2^-16)
    float* pv = pu + (size_t)BB * NC * HH;         // [B][H][ND]  = 1 MB

    proj_fused_kernel<<<dim3(DRUG_BLKS + CELL_BLKS, BB), 256, 0, stream>>>(
        cell, drug, w_q, w_k, bias, pu, pv);
    coattn_kernel<<<dim3(ND / 512, NC / CHUNK, BB), 256, 0, stream>>>(pu, pv, a, out);
}